// Round 1
// baseline (1075.129 us; speedup 1.0000x reference)
//
#include <hip/hip_runtime.h>

#define NPTS 65536
#define VH 176
#define VW 176
#define VD 132
#define FD 32

typedef _Float16 half8 __attribute__((ext_vector_type(8)));
typedef float f32x4 __attribute__((ext_vector_type(4)));

struct Params {
    const float* W[10];
    const float* b[10];
};

__device__ __forceinline__ float sp100(float x) {
    if (x > 0.2f) return x;
    float e = __expf(x * 100.0f);
    return __logf(1.0f + e) * 0.01f;
}

// ---------------- Kernel A: query layer -> feat[N,32], sum|bias| ----------------
// 32 lanes per point (lane = feature f), 8 points per 256-thread block.
__global__ __launch_bounds__(256) void query_kernel(
    const float* __restrict__ pixel, const float* __restrict__ vol,
    const float* __restrict__ Wq, const float* __restrict__ bq,
    float* __restrict__ feat_out, float* __restrict__ sum_abs)
{
    const int tid = threadIdx.x;
    const int f = tid & 31;
    const int p = blockIdx.x * 8 + (tid >> 5);

    const float qx = pixel[p*3+0] + 24.0f;
    const float qy = pixel[p*3+1] + 24.0f;
    const float qz = (pixel[p*3+2] - 425.0f) / 480.0f * 128.0f;
    const int bx = (int)floorf(qx);
    const int by = (int)floorf(qy);
    const int bz = (int)floorf(qz);

    // sim normalization cancels in feat normalization -> use raw sim.
    float mixed = 0.0f;
    #pragma unroll
    for (int dx = 0; dx < 4; ++dx) {
        const int i0 = bx + dx - 1;
        const float sx = (float)i0 * qx;
        #pragma unroll
        for (int dy = 0; dy < 4; ++dy) {
            const int i1 = by + dy - 1;
            const int rowbase = (i0 * VW + i1) * VD;
            const float sxy = sx + (float)i1 * qy;
            #pragma unroll
            for (int dz = 0; dz < 4; ++dz) {
                const int i2 = bz + dz - 1;
                const float sim = sxy + (float)i2 * qz;
                const float v = vol[(rowbase + i2) * FD + f];
                mixed = fmaf(sim, v, mixed);
            }
        }
    }
    float tot = mixed;
    #pragma unroll
    for (int m = 16; m >= 1; m >>= 1) tot += __shfl_xor(tot, m, 32);
    const float feat = mixed / tot;
    feat_out[p*32 + f] = feat;

    // bias = Wq @ feat + bq ; accumulate sum(|bias|) for the global mean
    float a0 = bq[f], a1 = bq[f+32], a2 = bq[f+64], a3 = bq[f+96];
    #pragma unroll
    for (int ff = 0; ff < 32; ++ff) {
        const float fv = __shfl(feat, ff, 32);
        a0 = fmaf(Wq[(f     )*32 + ff], fv, a0);
        a1 = fmaf(Wq[(f + 32)*32 + ff], fv, a1);
        a2 = fmaf(Wq[(f + 64)*32 + ff], fv, a2);
        a3 = fmaf(Wq[(f + 96)*32 + ff], fv, a3);
    }
    float s = fabsf(a0) + fabsf(a1) + fabsf(a2) + fabsf(a3);
    #pragma unroll
    for (int m = 32; m >= 1; m >>= 1) s += __shfl_xor(s, m, 64);
    __shared__ float part[4];
    if ((tid & 63) == 0) part[tid >> 6] = s;
    __syncthreads();
    if (tid == 0) atomicAdd(sum_abs, part[0] + part[1] + part[2] + part[3]);
}

// ---------------- Kernel B: MLP with fp16 MFMA ----------------
// Block: 256 threads (4 waves), 64 points. Wave w owns act rows [16w,16w+16).
__global__ __launch_bounds__(256) void mlp_kernel(
    const float* __restrict__ world, const float* __restrict__ feat,
    const float* __restrict__ Wq, const float* __restrict__ bq,
    const float* __restrict__ sum_abs, float* __restrict__ out, Params P)
{
    __shared__ __align__(16) _Float16 wbuf[128 * 136];
    __shared__ __align__(16) _Float16 act[64 * 136];
    __shared__ float bbuf[128];
    __shared__ float wld[64 * 4];
    __shared__ float wrow[128];

    const int tid = threadIdx.x;
    const int lane = tid & 63;
    const int wid = tid >> 6;
    const int m0 = blockIdx.x * 64;

    if (tid < 192) wld[(tid/3)*4 + (tid % 3)] = world[(m0 + tid/3)*3 + (tid % 3)];

    const float inv_mean = (float)NPTS * 128.0f / sum_abs[0];

    // ---- layer 0: h = world@W0^T + b0, * (bias/mean|bias|), softplus ----
    {
        const int m = tid >> 2;
        const int c0 = (tid & 3) * 32;
        float fv[32];
        #pragma unroll
        for (int i = 0; i < 32; ++i) fv[i] = feat[(m0 + m)*32 + i];
        const float wx = world[(m0+m)*3+0];
        const float wy = world[(m0+m)*3+1];
        const float wz = world[(m0+m)*3+2];
        for (int j = 0; j < 32; ++j) {
            const int c = c0 + j;
            float bias = bq[c];
            #pragma unroll
            for (int i = 0; i < 32; ++i) bias = fmaf(Wq[c*32 + i], fv[i], bias);
            const float h = P.b[0][c] + P.W[0][c*3+0]*wx + P.W[0][c*3+1]*wy + P.W[0][c*3+2]*wz;
            act[m*136 + c] = (_Float16)sp100(h * bias * inv_mean);
        }
    }

    const int ar = (wid*16 + (lane & 15)) * 136 + ((lane >> 4) * 8);
    const int brb = (lane & 15) * 136 + ((lane >> 4) * 8);
    const int erow = wid*16 + ((lane >> 4) * 4);
    const int ecol0 = lane & 15;

    // ---- layers 1..8 ----
    #pragma unroll 1
    for (int l = 1; l <= 8; ++l) {
        const float* Wl = P.W[l];
        const float* bl = P.b[l];
        const int rows = (l == 4) ? 125 : 128;
        __syncthreads();
        #pragma unroll
        for (int i = tid; i < 4096; i += 256) {
            const int r = i >> 5;
            const int c4 = (i & 31) << 2;
            float4 w = make_float4(0.f, 0.f, 0.f, 0.f);
            if (r < rows) w = ((const float4*)Wl)[r*32 + (i & 31)];
            _Float16* d = &wbuf[r*136 + c4];
            d[0] = (_Float16)w.x; d[1] = (_Float16)w.y;
            d[2] = (_Float16)w.z; d[3] = (_Float16)w.w;
        }
        if (tid < 128) bbuf[tid] = (tid < rows) ? bl[tid] : 0.0f;
        __syncthreads();

        half8 a[4];
        #pragma unroll
        for (int c = 0; c < 4; ++c) a[c] = *(const half8*)&act[ar + c*32];

        f32x4 acc[8] = {};
        #pragma unroll
        for (int c = 0; c < 4; ++c) {
            #pragma unroll
            for (int ot = 0; ot < 8; ++ot) {
                const half8 bf = *(const half8*)&wbuf[brb + ot*16*136 + c*32];
                acc[ot] = __builtin_amdgcn_mfma_f32_16x16x32_f16(a[c], bf, acc[ot], 0, 0, 0);
            }
        }
        #pragma unroll
        for (int ot = 0; ot < 8; ++ot) {
            const int col = ot*16 + ecol0;
            #pragma unroll
            for (int r = 0; r < 4; ++r) {
                float v = acc[ot][r] + bbuf[col];
                if (l == 4 && col >= 125) v = wld[(erow + r)*4 + (col - 125)];
                act[(erow + r)*136 + col] = (_Float16)sp100(v);
            }
        }
    }

    // ---- layer 9: two 128-col halves, no softplus, fp32 out ----
    #pragma unroll 1
    for (int hh = 0; hh < 2; ++hh) {
        __syncthreads();
        #pragma unroll
        for (int i = tid; i < 4096; i += 256) {
            const int r = i >> 5;
            const int c4 = (i & 31) << 2;
            const float4 w = ((const float4*)P.W[9])[(hh*128 + r)*32 + (i & 31)];
            _Float16* d = &wbuf[r*136 + c4];
            d[0] = (_Float16)w.x; d[1] = (_Float16)w.y;
            d[2] = (_Float16)w.z; d[3] = (_Float16)w.w;
        }
        if (tid < 128) bbuf[tid] = P.b[9][hh*128 + tid];
        __syncthreads();

        half8 a[4];
        #pragma unroll
        for (int c = 0; c < 4; ++c) a[c] = *(const half8*)&act[ar + c*32];

        f32x4 acc[8] = {};
        #pragma unroll
        for (int c = 0; c < 4; ++c) {
            #pragma unroll
            for (int ot = 0; ot < 8; ++ot) {
                const half8 bf = *(const half8*)&wbuf[brb + ot*16*136 + c*32];
                acc[ot] = __builtin_amdgcn_mfma_f32_16x16x32_f16(a[c], bf, acc[ot], 0, 0, 0);
            }
        }
        #pragma unroll
        for (int ot = 0; ot < 8; ++ot) {
            const int col = ot*16 + ecol0;
            #pragma unroll
            for (int r = 0; r < 4; ++r) {
                out[(size_t)(m0 + erow + r)*257 + hh*128 + col] = acc[ot][r] + bbuf[col];
            }
        }
    }

    // ---- output column 256 ----
    __syncthreads();
    if (tid < 128) wrow[tid] = P.W[9][256*128 + tid];
    __syncthreads();
    if (tid < 64) {
        float s = P.b[9][256];
        #pragma unroll 16
        for (int k = 0; k < 128; ++k)
            s = fmaf((float)act[tid*136 + k], wrow[k], s);
        out[(size_t)(m0 + tid)*257 + 256] = s;
    }
}

extern "C" void kernel_launch(void* const* d_in, const int* in_sizes, int n_in,
                              void* d_out, int out_size, void* d_ws, size_t ws_size,
                              hipStream_t stream) {
    const float* world = (const float*)d_in[0];
    const float* pixel = (const float*)d_in[1];
    const float* vol   = (const float*)d_in[2];
    const float* Wq    = (const float*)d_in[3];
    const float* bq    = (const float*)d_in[4];
    Params P;
    for (int l = 0; l < 10; ++l) {
        P.W[l] = (const float*)d_in[5 + 2*l];
        P.b[l] = (const float*)d_in[6 + 2*l];
    }
    float* sum_abs = (float*)d_ws;
    float* featbuf = (float*)((char*)d_ws + 256);

    hipMemsetAsync(d_ws, 0, 256, stream);
    query_kernel<<<NPTS/8, 256, 0, stream>>>(pixel, vol, Wq, bq, featbuf, sum_abs);
    mlp_kernel<<<NPTS/64, 256, 0, stream>>>(world, featbuf, Wq, bq, sum_abs,
                                            (float*)d_out, P);
}

// Round 2
// 926.631 us; speedup vs baseline: 1.1603x; 1.1603x over previous
//
#include <hip/hip_runtime.h>

#define NPTS 65536
#define VW 176
#define VD 132
#define FD 32

typedef _Float16 half8 __attribute__((ext_vector_type(8)));
typedef float f32x4 __attribute__((ext_vector_type(4)));

// fp16 weight cache layout (offsets in halfs), lives in d_ws
#define OFF_WQ 0
#define OFF_L1 4096                      // layers 1..8: OFF_L1 + (l-1)*16384
#define OFF_L9 (4096 + 8 * 16384)        // W9 rows 0..255
#define W16_TOTAL (4096 + 8 * 16384 + 32768)

struct Params {
    const float* W[10];
    const float* b[10];
};

__device__ __forceinline__ float sp100(float x) {
    if (x > 0.2f) return x;
    float e = __expf(x * 100.0f);
    return __logf(1.0f + e) * 0.01f;
}

// ---------------- Kernel P: fp32 -> fp16 weight cache ----------------
__global__ __launch_bounds__(256) void prep_kernel(Params P, const float* __restrict__ Wq,
                                                   _Float16* __restrict__ w16) {
    const int i = blockIdx.x * 256 + threadIdx.x;
    if (i >= W16_TOTAL) return;
    if (i < 4096) { w16[i] = (_Float16)Wq[i]; return; }
    int j = i - 4096;
    if (j < 8 * 16384) {
        const int l = (j >> 14) + 1;
        const int r = (j & 16383) >> 7;
        float v = 0.0f;
        if (l != 4) v = P.W[l][j & 16383];
        else if (r < 125) v = P.W[4][j & 16383];   // pad rows 125..127 with 0
        w16[i] = (_Float16)v;
        return;
    }
    j -= 8 * 16384;
    w16[i] = (_Float16)P.W[9][j];                  // W9 rows 0..255
}

// ---------------- Kernel A: query layer -> feat16[N,32], sum|bias| ----------------
// 32 lanes per point (lane = feature f), 8 points per 256-thread block.
__global__ __launch_bounds__(256) void query_kernel(
    const float* __restrict__ pixel, const float* __restrict__ vol,
    const float* __restrict__ Wq, const float* __restrict__ bq,
    _Float16* __restrict__ feat_out, float* __restrict__ sum_abs)
{
    const int tid = threadIdx.x;
    const int f = tid & 31;
    const int p = blockIdx.x * 8 + (tid >> 5);

    const float qx = pixel[p*3+0] + 24.0f;
    const float qy = pixel[p*3+1] + 24.0f;
    const float qz = (pixel[p*3+2] - 425.0f) / 480.0f * 128.0f;
    const int bx = (int)floorf(qx);
    const int by = (int)floorf(qy);
    const int bz = (int)floorf(qz);

    // sim normalization cancels in feat normalization -> use raw sim.
    float mix0 = 0.0f, mix1 = 0.0f;   // 2 accumulators for ILP
    #pragma unroll
    for (int dx = 0; dx < 4; ++dx) {
        const int i0 = bx + dx - 1;
        const float sx = (float)i0 * qx;
        #pragma unroll
        for (int dy = 0; dy < 4; ++dy) {
            const int i1 = by + dy - 1;
            const int rowbase = (i0 * VW + i1) * VD;
            const float sxy = sx + (float)i1 * qy;
            #pragma unroll
            for (int dz = 0; dz < 4; ++dz) {
                const int i2 = bz + dz - 1;
                const float sim = sxy + (float)i2 * qz;
                const float v = vol[(rowbase + i2) * FD + f];
                if (dx < 2) mix0 = fmaf(sim, v, mix0);
                else        mix1 = fmaf(sim, v, mix1);
            }
        }
    }
    const float mixed = mix0 + mix1;
    float tot = mixed;
    #pragma unroll
    for (int m = 16; m >= 1; m >>= 1) tot += __shfl_xor(tot, m, 32);
    const float feat = mixed / tot;
    feat_out[p*32 + f] = (_Float16)feat;

    // bias = Wq @ feat + bq ; accumulate sum(|bias|) for the global mean (fp32)
    float a0 = bq[f], a1 = bq[f+32], a2 = bq[f+64], a3 = bq[f+96];
    #pragma unroll
    for (int ff = 0; ff < 32; ++ff) {
        const float fv = __shfl(feat, ff, 32);
        a0 = fmaf(Wq[(f     )*32 + ff], fv, a0);
        a1 = fmaf(Wq[(f + 32)*32 + ff], fv, a1);
        a2 = fmaf(Wq[(f + 64)*32 + ff], fv, a2);
        a3 = fmaf(Wq[(f + 96)*32 + ff], fv, a3);
    }
    float s = fabsf(a0) + fabsf(a1) + fabsf(a2) + fabsf(a3);
    #pragma unroll
    for (int m = 32; m >= 1; m >>= 1) s += __shfl_xor(s, m, 64);
    __shared__ float part[4];
    if ((tid & 63) == 0) part[tid >> 6] = s;
    __syncthreads();
    if (tid == 0) atomicAdd(sum_abs, part[0] + part[1] + part[2] + part[3]);
}

// ---------------- Kernel B: MLP, fp16 MFMA, weights from global (L1/L2 broadcast) ----
// 256 threads = 4 independent waves; wave owns 16 points. No __syncthreads:
// the act LDS region is wave-private (D->A relayout stays within the wave's rows).
__global__ __launch_bounds__(256, 4) void mlp_kernel(
    const float* __restrict__ world, const _Float16* __restrict__ feat16,
    const _Float16* __restrict__ w16, const float* __restrict__ bq,
    const float* __restrict__ sum_abs, float* __restrict__ out, Params P)
{
    __shared__ __align__(16) _Float16 act[64 * 136];

    const int tid  = threadIdx.x;
    const int lane = tid & 63;
    const int wid  = tid >> 6;
    const int n16  = lane & 15;          // A.m / B.n / C.col
    const int kg   = lane >> 4;          // 0..3: A.k-group / C.row-group
    const int wrow0 = wid * 16;          // wave's local row base in act
    const int gm    = blockIdx.x * 64 + wrow0;  // wave's global point base
    const float inv_mean = (float)NPTS * 128.0f / sum_abs[0];

    // ---- layer 0: bias = feat@Wq^T+bq via MFMA (K=32); h = world@W0^T+b0 scalar ----
    {
        const half8 fa = *(const half8*)&feat16[(size_t)(gm + n16) * 32 + kg * 8];
        f32x4 acc[8];
        #pragma unroll
        for (int ot = 0; ot < 8; ++ot) {
            const half8 bf = *(const half8*)&w16[OFF_WQ + (ot*16 + n16) * 32 + kg * 8];
            f32x4 z = {};
            acc[ot] = __builtin_amdgcn_mfma_f32_16x16x32_f16(fa, bf, z, 0, 0, 0);
        }
        float w0x[8], w0y[8], w0z[8], b0a[8], bqa[8];
        #pragma unroll
        for (int ot = 0; ot < 8; ++ot) {
            const int col = ot*16 + n16;
            w0x[ot] = P.W[0][col*3+0]; w0y[ot] = P.W[0][col*3+1]; w0z[ot] = P.W[0][col*3+2];
            b0a[ot] = P.b[0][col];     bqa[ot] = bq[col];
        }
        #pragma unroll
        for (int r = 0; r < 4; ++r) {
            const int row = kg*4 + r;
            const float wx = world[(gm+row)*3+0];
            const float wy = world[(gm+row)*3+1];
            const float wz = world[(gm+row)*3+2];
            #pragma unroll
            for (int ot = 0; ot < 8; ++ot) {
                const float h = b0a[ot] + w0x[ot]*wx + w0y[ot]*wy + w0z[ot]*wz;
                const float bias = acc[ot][r] + bqa[ot];
                act[(wrow0+row)*136 + ot*16 + n16] = (_Float16)sp100(h * bias * inv_mean);
            }
        }
    }

    const int a_off = (wrow0 + n16) * 136 + kg * 8;

    // ---- layers 1..8 ----
    #pragma unroll 1
    for (int l = 1; l <= 8; ++l) {
        const _Float16* wl = &w16[OFF_L1 + (l - 1) * 16384];
        half8 a[4];
        #pragma unroll
        for (int c = 0; c < 4; ++c) a[c] = *(const half8*)&act[a_off + c*32];

        f32x4 acc[8] = {};
        #pragma unroll
        for (int c = 0; c < 4; ++c) {
            #pragma unroll
            for (int ot = 0; ot < 8; ++ot) {
                const half8 bf = *(const half8*)&wl[(ot*16 + n16)*128 + kg*8 + c*32];
                acc[ot] = __builtin_amdgcn_mfma_f32_16x16x32_f16(a[c], bf, acc[ot], 0, 0, 0);
            }
        }
        const bool l4 = (l == 4);
        float blv[8];
        #pragma unroll
        for (int ot = 0; ot < 8; ++ot) {
            const int col = ot*16 + n16;
            blv[ot] = (l4 && col >= 125) ? 0.0f : P.b[l][col];
        }
        #pragma unroll
        for (int ot = 0; ot < 8; ++ot) {
            const int col = ot*16 + n16;
            #pragma unroll
            for (int r = 0; r < 4; ++r) {
                const int row = kg*4 + r;
                float v = acc[ot][r] + blv[ot];
                if (l4 && col >= 125) v = world[(gm+row)*3 + (col - 125)];
                act[(wrow0+row)*136 + col] = (_Float16)sp100(v);
            }
        }
    }

    // ---- layer 9: 257 outputs = two 128-col MFMA halves + scalar col 256 ----
    {
        half8 a[4];
        #pragma unroll
        for (int c = 0; c < 4; ++c) a[c] = *(const half8*)&act[a_off + c*32];

        #pragma unroll 1
        for (int hh = 0; hh < 2; ++hh) {
            f32x4 acc[8] = {};
            #pragma unroll
            for (int c = 0; c < 4; ++c) {
                #pragma unroll
                for (int ot = 0; ot < 8; ++ot) {
                    const half8 bf = *(const half8*)&w16[OFF_L9 + (hh*128 + ot*16 + n16)*128 + kg*8 + c*32];
                    acc[ot] = __builtin_amdgcn_mfma_f32_16x16x32_f16(a[c], bf, acc[ot], 0, 0, 0);
                }
            }
            #pragma unroll
            for (int ot = 0; ot < 8; ++ot) {
                const int col = ot*16 + n16;
                const float b9 = P.b[9][hh*128 + col];
                #pragma unroll
                for (int r = 0; r < 4; ++r) {
                    out[(size_t)(gm + kg*4 + r)*257 + hh*128 + col] = acc[ot][r] + b9;
                }
            }
        }
    }
    // col 256: 4 lanes per point, 32 k each, shuffle-reduce
    {
        const int rr = lane >> 2;       // 0..15: local row
        const int q  = lane & 3;
        float s = 0.0f;
        #pragma unroll
        for (int j = 0; j < 32; ++j) {
            const int k = q*32 + j;
            s = fmaf((float)act[(wrow0 + rr)*136 + k], P.W[9][256*128 + k], s);
        }
        s += __shfl_xor(s, 1, 64);
        s += __shfl_xor(s, 2, 64);
        if (q == 0) out[(size_t)(gm + rr)*257 + 256] = P.b[9][256] + s;
    }
}

extern "C" void kernel_launch(void* const* d_in, const int* in_sizes, int n_in,
                              void* d_out, int out_size, void* d_ws, size_t ws_size,
                              hipStream_t stream) {
    const float* world = (const float*)d_in[0];
    const float* pixel = (const float*)d_in[1];
    const float* vol   = (const float*)d_in[2];
    const float* Wq    = (const float*)d_in[3];
    const float* bq    = (const float*)d_in[4];
    Params P;
    for (int l = 0; l < 10; ++l) {
        P.W[l] = (const float*)d_in[5 + 2*l];
        P.b[l] = (const float*)d_in[6 + 2*l];
    }
    float*    sum_abs = (float*)d_ws;
    _Float16* feat16  = (_Float16*)((char*)d_ws + 4096);
    _Float16* w16     = (_Float16*)((char*)d_ws + 4096 + (size_t)NPTS * 32 * 2);

    hipMemsetAsync(d_ws, 0, 256, stream);
    prep_kernel<<<(W16_TOTAL + 255) / 256, 256, 0, stream>>>(P, Wq, w16);
    query_kernel<<<NPTS / 8, 256, 0, stream>>>(pixel, vol, Wq, bq, feat16, sum_abs);
    mlp_kernel<<<NPTS / 64, 256, 0, stream>>>(world, feat16, w16, bq, sum_abs,
                                              (float*)d_out, P);
}